// Round 1
// baseline (4326.645 us; speedup 1.0000x reference)
//
#include <hip/hip_runtime.h>
#include <stdint.h>

typedef __attribute__((ext_vector_type(8))) short bf16x8;
typedef __attribute__((ext_vector_type(4))) float fx4;
typedef unsigned short ush;

#define DEV __device__ __forceinline__

DEV unsigned short f2bf(float f) {
  unsigned u = __float_as_uint(f);
  u += 0x7fffu + ((u >> 16) & 1u);
  return (unsigned short)(u >> 16);
}

DEV void async16(const void* g, void* l) {
  __builtin_amdgcn_global_load_lds(
      (const __attribute__((address_space(1))) unsigned*)g,
      (__attribute__((address_space(3))) unsigned*)l, 16, 0, 0);
}

// ---------------- weight prep: fp32 (K,N) -> bf16 (N,K) transposed ----------
// per-layer packed layout (elements): [QKV^T 3*512*512][Wo^T 512*512]
//                                     [W1^T 2048*512][W2^T 512*2048]
#define WSTRIDE 3145728

__global__ __launch_bounds__(256) void k_prep_weights(
    const float* __restrict__ Wq, const float* __restrict__ Wk,
    const float* __restrict__ Wv, const float* __restrict__ Wo,
    const float* __restrict__ W1, const float* __restrict__ W2,
    ush* __restrict__ wbf) {
  __shared__ float tile[32][33];
  int bid = blockIdx.x;
  int l = bid / 3072, r = bid % 3072;
  const float* src; ush* dst; int R, Cc, t;
  if (r < 768) {
    int w = r >> 8; t = r & 255; R = 512; Cc = 512;
    src = (w == 0 ? Wq : (w == 1 ? Wk : Wv)) + (size_t)l * 262144;
    dst = wbf + (size_t)l * WSTRIDE + w * 262144;
  } else if (r < 1024) {
    t = r - 768; R = 512; Cc = 512;
    src = Wo + (size_t)l * 262144; dst = wbf + (size_t)l * WSTRIDE + 786432;
  } else if (r < 2048) {
    t = r - 1024; R = 512; Cc = 2048;
    src = W1 + (size_t)l * 1048576; dst = wbf + (size_t)l * WSTRIDE + 1048576;
  } else {
    t = r - 2048; R = 2048; Cc = 512;
    src = W2 + (size_t)l * 1048576; dst = wbf + (size_t)l * WSTRIDE + 2097152;
  }
  int tpr = Cc >> 5;
  int trow = t / tpr, tcol = t % tpr;
  int tx = threadIdx.x & 31, ty = threadIdx.x >> 5;
#pragma unroll
  for (int i = 0; i < 4; i++) {
    int rr = trow * 32 + ty + i * 8, cc = tcol * 32 + tx;
    tile[ty + i * 8][tx] = src[(size_t)rr * Cc + cc];
  }
  __syncthreads();
#pragma unroll
  for (int i = 0; i < 4; i++) {
    int cc = tcol * 32 + ty + i * 8, rr = trow * 32 + tx;
    dst[(size_t)cc * R + rr] = f2bf(tile[tx][ty + i * 8]);
  }
}

__global__ __launch_bounds__(256) void k_pack_bias(
    const float* __restrict__ bq, const float* __restrict__ bk,
    const float* __restrict__ bv, float* __restrict__ dst) {
  int idx = blockIdx.x * 256 + threadIdx.x;
  if (idx >= 6 * 1536) return;
  int l = idx / 1536, r = idx % 1536;
  float v = (r < 512) ? bq[l * 512 + r]
            : (r < 1024) ? bk[l * 512 + r - 512] : bv[l * 512 + r - 1024];
  dst[idx] = v;
}

// ---------------- embed: (B,C,HW) transpose -> x (B,T,C) + pos --------------
__global__ __launch_bounds__(256) void k_embed(
    const float* __restrict__ img, const float* __restrict__ rad,
    const float* __restrict__ pos, float* __restrict__ x) {
  __shared__ float tile[32][33];
  int bid = blockIdx.x;
  int b = bid / 640, r2 = bid % 640;
  int tc = r2 / 40, tt = r2 % 40;
  int tx = threadIdx.x & 31, ty = threadIdx.x >> 5;
#pragma unroll
  for (int i = 0; i < 4; i++) {
    int c = tc * 32 + ty + i * 8, t = tt * 32 + tx;
    float v = (t < 1024) ? img[(size_t)(b * 512 + c) * 1024 + t]
                         : rad[(size_t)(b * 512 + c) * 256 + (t - 1024)];
    tile[ty + i * 8][tx] = v;
  }
  __syncthreads();
#pragma unroll
  for (int i = 0; i < 4; i++) {
    int t = tt * 32 + ty + i * 8, c = tc * 32 + tx;
    x[(size_t)(b * 1280 + t) * 512 + c] = tile[tx][ty + i * 8] + pos[(size_t)t * 512 + c];
  }
}

// ---------------- layernorm: one wave per row (C=512) -----------------------
__global__ __launch_bounds__(256) void k_ln_bf16(
    const float* __restrict__ x, const float* __restrict__ w,
    const float* __restrict__ bia, ush* __restrict__ h) {
  int wave = threadIdx.x >> 6, lane = threadIdx.x & 63;
  int row = blockIdx.x * 4 + wave;
  int c0 = lane * 8;
  const float4* xr = (const float4*)(x + (size_t)row * 512 + c0);
  float4 a = xr[0], b4 = xr[1];
  float v[8] = {a.x, a.y, a.z, a.w, b4.x, b4.y, b4.z, b4.w};
  float s = 0.f, s2 = 0.f;
#pragma unroll
  for (int e = 0; e < 8; e++) { s += v[e]; s2 += v[e] * v[e]; }
#pragma unroll
  for (int mask = 1; mask < 64; mask <<= 1) {
    s += __shfl_xor(s, mask, 64);
    s2 += __shfl_xor(s2, mask, 64);
  }
  float mean = s * (1.f / 512.f);
  float var = s2 * (1.f / 512.f) - mean * mean;
  float rstd = rsqrtf(var + 1e-5f);
  bf16x8 o;
#pragma unroll
  for (int e = 0; e < 8; e++)
    o[e] = (short)f2bf((v[e] - mean) * rstd * w[c0 + e] + bia[c0 + e]);
  *(bf16x8*)(h + (size_t)row * 512 + c0) = o;
}

__global__ __launch_bounds__(256) void k_ln_final(
    const float* __restrict__ x, const float* __restrict__ w,
    const float* __restrict__ bia, float* __restrict__ out) {
  int wave = threadIdx.x >> 6, lane = threadIdx.x & 63;
  int row = blockIdx.x * 4 + wave;
  int c0 = lane * 8;
  const float4* xr = (const float4*)(x + (size_t)row * 512 + c0);
  float4 a = xr[0], b4 = xr[1];
  float v[8] = {a.x, a.y, a.z, a.w, b4.x, b4.y, b4.z, b4.w};
  float s = 0.f, s2 = 0.f;
#pragma unroll
  for (int e = 0; e < 8; e++) { s += v[e]; s2 += v[e] * v[e]; }
#pragma unroll
  for (int mask = 1; mask < 64; mask <<= 1) {
    s += __shfl_xor(s, mask, 64);
    s2 += __shfl_xor(s2, mask, 64);
  }
  float mean = s * (1.f / 512.f);
  float var = s2 * (1.f / 512.f) - mean * mean;
  float rstd = rsqrtf(var + 1e-5f);
  int b = row / 1280, t = row % 1280;
  size_t orow = (t < 1024) ? ((size_t)b * 1024 + t)
                           : (16384 + (size_t)b * 256 + (t - 1024));
  float o[8];
#pragma unroll
  for (int e = 0; e < 8; e++)
    o[e] = (v[e] - mean) * rstd * w[c0 + e] + bia[c0 + e];
  float4* op = (float4*)(out + orow * 512 + c0);
  op[0] = make_float4(o[0], o[1], o[2], o[3]);
  op[1] = make_float4(o[4], o[5], o[6], o[7]);
}

// ---------------- GEMM: A (M,K) bf16 row-major @ Wt (N,K) bf16 row-major ----
// MODE 0: out bf16; MODE 1: out bf16 + ReLU; MODE 2: fp32 residual += (into outv)
template <int MODE>
__global__ __launch_bounds__(256) void k_gemm(
    const ush* __restrict__ A, const ush* __restrict__ Wt,
    const float* __restrict__ bias, void* __restrict__ outv,
    int M, int N, int K) {
  __shared__ char smem[32768];
  char* As = smem;
  char* Bs = smem + 16384;
  const int tid = threadIdx.x;
  const int m0 = blockIdx.y << 7, n0 = blockIdx.x << 7;
  const int lane = tid & 63, wave = tid >> 6;
  const int quad = lane >> 4, l16 = lane & 15;
  const int m_off = (wave & 1) << 6, n_off = (wave >> 1) << 6;
  fx4 acc[4][4];
#pragma unroll
  for (int a = 0; a < 4; a++)
#pragma unroll
    for (int b = 0; b < 4; b++) acc[a][b] = (fx4){0.f, 0.f, 0.f, 0.f};

  for (int k0 = 0; k0 < K; k0 += 64) {
#pragma unroll
    for (int j = 0; j < 4; j++) {
      int f = (j << 8) + tid;
      int row = f >> 3, cph = f & 7;
      int clog = cph ^ (row & 7);
      async16(A + (size_t)(m0 + row) * K + k0 + (clog << 3), As + (f << 4));
    }
#pragma unroll
    for (int j = 0; j < 4; j++) {
      int f = (j << 8) + tid;
      int row = f >> 3, cph = f & 7;
      int clog = cph ^ (row & 7);
      async16(Wt + (size_t)(n0 + row) * K + k0 + (clog << 3), Bs + (f << 4));
    }
    __syncthreads();
#pragma unroll
    for (int ks = 0; ks < 2; ks++) {
      const int chunk = (ks << 2) + quad;
      bf16x8 af[4], bfr[4];
#pragma unroll
      for (int mb = 0; mb < 4; mb++) {
        int rw = m_off + (mb << 4) + l16;
        af[mb] = *(const bf16x8*)(As + rw * 128 + ((chunk ^ (rw & 7)) << 4));
      }
#pragma unroll
      for (int nb = 0; nb < 4; nb++) {
        int rw = n_off + (nb << 4) + l16;
        bfr[nb] = *(const bf16x8*)(Bs + rw * 128 + ((chunk ^ (rw & 7)) << 4));
      }
#pragma unroll
      for (int mb = 0; mb < 4; mb++)
#pragma unroll
        for (int nb = 0; nb < 4; nb++)
          acc[mb][nb] = __builtin_amdgcn_mfma_f32_16x16x32_bf16(
              af[mb], bfr[nb], acc[mb][nb], 0, 0, 0);
    }
    __syncthreads();
  }
#pragma unroll
  for (int mb = 0; mb < 4; mb++) {
#pragma unroll
    for (int nb = 0; nb < 4; nb++) {
      int col = n0 + n_off + (nb << 4) + l16;
      float bval = bias[col];
#pragma unroll
      for (int i = 0; i < 4; i++) {
        int row = m0 + m_off + (mb << 4) + (quad << 2) + i;
        float v = acc[mb][nb][i] + bval;
        if (MODE == 1) v = fmaxf(v, 0.f);
        if (MODE <= 1) {
          ((ush*)outv)[(size_t)row * N + col] = f2bf(v);
        } else {
          float* X = (float*)outv;
          size_t idx = (size_t)row * N + col;
          X[idx] += v;
        }
      }
    }
  }
}

// ---------------- V transpose: qkv v-cols -> vt (B, C, T) bf16 --------------
__global__ __launch_bounds__(256) void k_vt(const ush* __restrict__ qkv,
                                            ush* __restrict__ vt) {
  __shared__ ush tile[32][33];
  int bid = blockIdx.x;
  int b = bid / 640, r2 = bid % 640;
  int tc = r2 / 40, tt = r2 % 40;
  int tx = threadIdx.x & 31, ty = threadIdx.x >> 5;
#pragma unroll
  for (int i = 0; i < 4; i++) {
    int t = tt * 32 + ty + i * 8, c = tc * 32 + tx;
    tile[ty + i * 8][tx] = qkv[(size_t)(b * 1280 + t) * 1536 + 1024 + c];
  }
  __syncthreads();
#pragma unroll
  for (int i = 0; i < 4; i++) {
    int c = tc * 32 + ty + i * 8, t = tt * 32 + tx;
    vt[(size_t)(b * 512 + c) * 1280 + t] = tile[tx][ty + i * 8];
  }
}

// ---------------- flash attention: 64 q-rows/block, 16/wave -----------------
__global__ __launch_bounds__(256) void k_attn(const ush* __restrict__ qkv,
                                              const ush* __restrict__ vt,
                                              ush* __restrict__ y) {
  __shared__ char pmem[8192];
  int qt = blockIdx.x;        // 0..19
  int bh = blockIdx.y;        // 0..127
  int b = bh >> 3, h = bh & 7;
  int tid = threadIdx.x, lane = tid & 63, wave = tid >> 6;
  int quad = lane >> 4, l16 = lane & 15;
  int qbase = qt * 64 + wave * 16;
  char* pb = pmem + wave * 2048;
  const float scale = 0.125f;

  // Q fragments (A-operand): row m=l16, k=quad*8+j
  const ush* qp = qkv + (size_t)(b * 1280 + qbase + l16) * 1536 + h * 64 + quad * 8;
  bf16x8 aq0 = *(const bf16x8*)qp;
  bf16x8 aq1 = *(const bf16x8*)(qp + 32);

  fx4 yacc[4];
#pragma unroll
  for (int nb = 0; nb < 4; nb++) yacc[nb] = (fx4){0.f, 0.f, 0.f, 0.f};
  float m_run[4] = {-1e30f, -1e30f, -1e30f, -1e30f};
  float l_run[4] = {0.f, 0.f, 0.f, 0.f};

  for (int k0 = 0; k0 < 1280; k0 += 64) {
    fx4 s[4];
#pragma unroll
    for (int nb = 0; nb < 4; nb++) s[nb] = (fx4){0.f, 0.f, 0.f, 0.f};
#pragma unroll
    for (int nb = 0; nb < 4; nb++) {
      const ush* kp = qkv + (size_t)(b * 1280 + k0 + nb * 16 + l16) * 1536 + 512 + h * 64 + quad * 8;
      bf16x8 bk0 = *(const bf16x8*)kp;
      bf16x8 bk1 = *(const bf16x8*)(kp + 32);
      s[nb] = __builtin_amdgcn_mfma_f32_16x16x32_bf16(aq0, bk0, s[nb], 0, 0, 0);
      s[nb] = __builtin_amdgcn_mfma_f32_16x16x32_bf16(aq1, bk1, s[nb], 0, 0, 0);
    }
    // online softmax (rows quad*4+i, reduce across the 16-lane column group)
    float mx[4];
#pragma unroll
    for (int i = 0; i < 4; i++)
      mx[i] = fmaxf(fmaxf(s[0][i], s[1][i]), fmaxf(s[2][i], s[3][i])) * scale;
#pragma unroll
    for (int mask = 1; mask < 16; mask <<= 1)
#pragma unroll
      for (int i = 0; i < 4; i++)
        mx[i] = fmaxf(mx[i], __shfl_xor(mx[i], mask, 64));
    float alpha[4];
#pragma unroll
    for (int i = 0; i < 4; i++) {
      float mn = fmaxf(m_run[i], mx[i]);
      alpha[i] = __expf(m_run[i] - mn);
      m_run[i] = mn;
    }
    float rsum[4] = {0.f, 0.f, 0.f, 0.f};
    float pval[4][4];
#pragma unroll
    for (int nb = 0; nb < 4; nb++)
#pragma unroll
      for (int i = 0; i < 4; i++) {
        float p = __expf(s[nb][i] * scale - m_run[i]);
        pval[nb][i] = p;
        rsum[i] += p;
      }
#pragma unroll
    for (int mask = 1; mask < 16; mask <<= 1)
#pragma unroll
      for (int i = 0; i < 4; i++) rsum[i] += __shfl_xor(rsum[i], mask, 64);
#pragma unroll
    for (int i = 0; i < 4; i++) l_run[i] = l_run[i] * alpha[i] + rsum[i];
#pragma unroll
    for (int nb = 0; nb < 4; nb++)
#pragma unroll
      for (int i = 0; i < 4; i++) yacc[nb][i] *= alpha[i];
    // P -> LDS (C-layout to A-layout transpose), swizzled rows of 128B
#pragma unroll
    for (int nb = 0; nb < 4; nb++)
#pragma unroll
      for (int i = 0; i < 4; i++) {
        int row = quad * 4 + i, col = nb * 16 + l16;
        int chunk = col >> 3;
        *(ush*)(pb + row * 128 + ((chunk ^ (row & 7)) << 4) + ((col & 7) << 1)) =
            f2bf(pval[nb][i]);
      }
    __syncthreads();
    // PV: A=P (m=q,k=key), B=V^T-frag (k=key, n=d) straight from vt
#pragma unroll
    for (int ks = 0; ks < 2; ks++) {
      int ch = ks * 4 + quad;
      bf16x8 ap = *(const bf16x8*)(pb + l16 * 128 + ((ch ^ (l16 & 7)) << 4));
#pragma unroll
      for (int nb = 0; nb < 4; nb++) {
        const ush* vp = vt + (size_t)(b * 512 + h * 64 + nb * 16 + l16) * 1280 + k0 + ks * 32 + quad * 8;
        bf16x8 bv = *(const bf16x8*)vp;
        yacc[nb] = __builtin_amdgcn_mfma_f32_16x16x32_bf16(ap, bv, yacc[nb], 0, 0, 0);
      }
    }
    __syncthreads();
  }
#pragma unroll
  for (int nb = 0; nb < 4; nb++)
#pragma unroll
    for (int i = 0; i < 4; i++) {
      int t = qbase + quad * 4 + i;
      int col = h * 64 + nb * 16 + l16;
      y[(size_t)(b * 1280 + t) * 512 + col] = f2bf(yacc[nb][i] / l_run[i]);
    }
}

// ---------------- host ------------------------------------------------------
extern "C" void kernel_launch(void* const* d_in, const int* in_sizes, int n_in,
                              void* d_out, int out_size, void* d_ws, size_t ws_size,
                              hipStream_t stream) {
  const float* img = (const float*)d_in[0];
  const float* rad = (const float*)d_in[1];
  const float* pos = (const float*)d_in[2];
  const float* ln1w = (const float*)d_in[3];
  const float* ln1b = (const float*)d_in[4];
  const float* Wq = (const float*)d_in[5];
  const float* bq = (const float*)d_in[6];
  const float* Wk = (const float*)d_in[7];
  const float* bk = (const float*)d_in[8];
  const float* Wv = (const float*)d_in[9];
  const float* bv = (const float*)d_in[10];
  const float* Wo = (const float*)d_in[11];
  const float* bo = (const float*)d_in[12];
  const float* ln2w = (const float*)d_in[13];
  const float* ln2b = (const float*)d_in[14];
  const float* W1 = (const float*)d_in[15];
  const float* b1 = (const float*)d_in[16];
  const float* W2 = (const float*)d_in[17];
  const float* b2 = (const float*)d_in[18];
  const float* lnfw = (const float*)d_in[19];
  const float* lnfb = (const float*)d_in[20];

  char* ws = (char*)d_ws;
  float* xw = (float*)(ws + 0);                  // 41,943,040 B  fp32 x (M,512)
  ush* h    = (ush*)(ws + 41943040);             // 20,971,520 B  bf16 h / vt alias
  ush* vt   = h;
  ush* qkv  = (ush*)(ws + 62914560);             // 62,914,560 B  bf16 qkv (M,1536)
  ush* y    = (ush*)(ws + 125829120);            // 20,971,520 B  bf16 y (M,512)
  ush* u    = qkv;                               // 83,886,080 B  bf16 u (M,2048) overlays qkv+y
  ush* wbf  = (ush*)(ws + 146800640);            // 37,748,736 B  bf16 weights^T
  float* qkvb = (float*)(ws + 184549376);        // 36,864 B      packed qkv bias

  k_prep_weights<<<18432, 256, 0, stream>>>(Wq, Wk, Wv, Wo, W1, W2, wbf);
  k_pack_bias<<<36, 256, 0, stream>>>(bq, bk, bv, qkvb);
  k_embed<<<10240, 256, 0, stream>>>(img, rad, pos, xw);

  for (int l = 0; l < 6; l++) {
    const ush* wl = wbf + (size_t)l * WSTRIDE;
    k_ln_bf16<<<5120, 256, 0, stream>>>(xw, ln1w + l * 512, ln1b + l * 512, h);
    k_gemm<0><<<dim3(12, 160), 256, 0, stream>>>(h, wl, qkvb + l * 1536, qkv, 20480, 1536, 512);
    k_vt<<<10240, 256, 0, stream>>>(qkv, vt);
    k_attn<<<dim3(20, 128), 256, 0, stream>>>(qkv, vt, y);
    k_gemm<2><<<dim3(4, 160), 256, 0, stream>>>(y, wl + 786432, bo + l * 512, xw, 20480, 512, 512);
    k_ln_bf16<<<5120, 256, 0, stream>>>(xw, ln2w + l * 512, ln2b + l * 512, h);
    k_gemm<1><<<dim3(16, 160), 256, 0, stream>>>(h, wl + 1048576, b1 + l * 2048, u, 20480, 2048, 512);
    k_gemm<2><<<dim3(4, 160), 256, 0, stream>>>(u, wl + 2097152, b2 + l * 512, xw, 20480, 512, 2048);
  }
  k_ln_final<<<5120, 256, 0, stream>>>(xw, lnfw, lnfb, (float*)d_out);
}